// Round 1
// baseline (782.408 us; speedup 1.0000x reference)
//
#include <hip/hip_runtime.h>
#include <hip/hip_bf16.h>

#define N_COARSE 12500
#define N_FINE   50000

typedef __bf16 bf16x8 __attribute__((ext_vector_type(8)));
typedef __bf16 bf16x4 __attribute__((ext_vector_type(4)));
typedef float  f32x4  __attribute__((ext_vector_type(4)));

// ---------------------------------------------------------------------------
// Shared MFMA GEMM core: one wave computes a 64-row x 64-col tile of
// C = A(f32)[M x lda] * B(bf16, fragment-packed [K/8][N][8]).
// Fragment conventions (gfx950 v_mfma_f32_16x16x32_bf16):
//   a-frag: lane holds A[row = lane&15][k = (lane>>4)*8 + j], j=0..7
//   b-frag: lane holds B[k = (lane>>4)*8 + j][col = lane&15]
//   d     : lane holds D[row = (lane>>4)*4 + j][col = lane&15]   (HW-verified)
// Only the relative A/B k-ordering matters for correctness (any consistent
// bijection sums the same dot product); C/D layout is the verified one.
// ---------------------------------------------------------------------------
__device__ __forceinline__ bf16x8 pack_a8(const float* p) {
    f32x4 x = *(const f32x4*)p;
    f32x4 y = *(const f32x4*)(p + 4);
    bf16x8 r;
    r[0] = (__bf16)x[0]; r[1] = (__bf16)x[1]; r[2] = (__bf16)x[2]; r[3] = (__bf16)x[3];
    r[4] = (__bf16)y[0]; r[5] = (__bf16)y[1]; r[6] = (__bf16)y[2]; r[7] = (__bf16)y[3];
    return r;
}

__device__ __forceinline__ void gemm_range(
    const float* __restrict__ A, int lda, int M, int row0,
    const bf16x8* __restrict__ packB, int N, int c0,
    int ks_begin, int ks_end,
    f32x4 (&acc)[4][4], int lane)
{
    const int g = lane >> 4, r15 = lane & 15;
    for (int ks = ks_begin; ks < ks_end; ++ks) {
        bf16x8 a[4];
        const int ka = (ks - ks_begin) * 32 + g * 8;
        #pragma unroll
        for (int rt = 0; rt < 4; ++rt) {
            int r = row0 + rt * 16 + r15;
            if (r > M - 1) r = M - 1;              // clamp tail rows (stores predicated)
            a[rt] = pack_a8(A + (size_t)r * lda + ka);
        }
        const size_t kb = (size_t)(ks * 4 + g) * N;
        #pragma unroll
        for (int ct = 0; ct < 4; ++ct) {
            bf16x8 b = packB[kb + c0 + ct * 16 + r15];
            #pragma unroll
            for (int rt = 0; rt < 4; ++rt)
                acc[rt][ct] = __builtin_amdgcn_mfma_f32_16x16x32_bf16(
                                  a[rt], b, acc[rt][ct], 0, 0, 0);
        }
    }
}

// ---------------------------------------------------------------------------
// Weight pre-pack: W(f32 row-major [K x N], starting at row_off) ->
// bf16 fragment layout dst[(k>>3)*N*8 + n*8 + (k&7)].
// ---------------------------------------------------------------------------
__global__ __launch_bounds__(256) void k_pack(const float* __restrict__ W,
                                              __bf16* __restrict__ dst,
                                              int K, int N, int row_off) {
    int idx = blockIdx.x * 256 + threadIdx.x;
    if (idx >= K * N) return;
    int k = idx / N, n = idx % N;
    dst[((size_t)(k >> 3) * N + n) * 8 + (k & 7)] = (__bf16)W[(size_t)(row_off + k) * N + n];
}

// ---------------------------------------------------------------------------
// Coarse: LE = last_equ @ W_last_equ, stored bf16 in the MFMA D-layout:
// LEp[(coarse*16 + colgrp)*64 + lane][j] with b = (lane>>4)*4 + j, col = colgrp*16 + (lane&15).
// This makes the fine kernel's gather a single coalesced 8B/lane load that
// matches the accumulator fragment element-for-element.
// ---------------------------------------------------------------------------
__global__ __launch_bounds__(256) void k_coarse_equ(
    const float* __restrict__ last_equ, const bf16x8* __restrict__ packW,
    __bf16* __restrict__ LEp)
{
    const int lane = threadIdx.x & 63, wid = threadIdx.x >> 6;
    const int row0 = blockIdx.x * 64;     // rows of the flattened [200000 x 256] A
    const int c0 = wid * 64;
    f32x4 acc[4][4] = {};
    gemm_range(last_equ, 256, N_COARSE * 16, row0, packW, 256, c0, 0, 8, acc, lane);
    #pragma unroll
    for (int rt = 0; rt < 4; ++rt) {
        int coarse = (row0 >> 4) + rt;    // 64 rows = 4 coarse points x 16 basis
        #pragma unroll
        for (int ct = 0; ct < 4; ++ct) {
            int cg = (c0 >> 4) + ct;
            bf16x4 v;
            v[0] = (__bf16)acc[rt][ct][0]; v[1] = (__bf16)acc[rt][ct][1];
            v[2] = (__bf16)acc[rt][ct][2]; v[3] = (__bf16)acc[rt][ct][3];
            *(bf16x4*)(LEp + ((size_t)(coarse * 16 + cg) * 64 + lane) * 4) = v;
        }
    }
}

// Coarse: LIW = last_inv @ W_mlp[0:256,:]  (plain f32 [12500 x 512])
__global__ __launch_bounds__(256) void k_coarse_inv(
    const float* __restrict__ last_inv, const bf16x8* __restrict__ packW,
    float* __restrict__ LIW)
{
    const int lane = threadIdx.x & 63, wid = threadIdx.x >> 6;
    const int row0 = blockIdx.x * 64;
    const int c0 = blockIdx.y * 256 + wid * 64;
    const int g = lane >> 4, r15 = lane & 15;
    f32x4 acc[4][4] = {};
    gemm_range(last_inv, 256, N_COARSE, row0, packW, 512, c0, 0, 8, acc, lane);
    #pragma unroll
    for (int rt = 0; rt < 4; ++rt)
        #pragma unroll
        for (int j = 0; j < 4; ++j) {
            int r = row0 + rt * 16 + g * 4 + j;
            if (r < N_COARSE)
                #pragma unroll
                for (int ct = 0; ct < 4; ++ct)
                    LIW[(size_t)r * 512 + c0 + ct * 16 + r15] = acc[rt][ct][j];
        }
}

// ---------------------------------------------------------------------------
// Fine fused: CE-tile = cur_equ @ W_cur_equ (MFMA), then multiply by gathered
// LE fragment (layout-matched), reduce over the 16 basis rows (4 in-lane +
// shfl_xor over lane-groups), write equ[n, col] = mean.
// 64 rows/block = 4 fine points x 16 basis -> basis-mean is block-internal.
// ---------------------------------------------------------------------------
__global__ __launch_bounds__(256) void k_fine_equ(
    const float* __restrict__ cur_equ, const bf16x8* __restrict__ packW,
    const __bf16* __restrict__ LEp, const int* __restrict__ up,
    float* __restrict__ equ)
{
    const int lane = threadIdx.x & 63, wid = threadIdx.x >> 6;
    const int row0 = blockIdx.x * 64;
    const int c0 = wid * 64;
    f32x4 acc[4][4] = {};
    gemm_range(cur_equ, 256, N_FINE * 16, row0, packW, 256, c0, 0, 8, acc, lane);
    const int n0 = row0 >> 4;
    #pragma unroll
    for (int rt = 0; rt < 4; ++rt) {
        int n = n0 + rt;
        int cu = up[n];
        #pragma unroll
        for (int ct = 0; ct < 4; ++ct) {
            int cg = (c0 >> 4) + ct;
            bf16x4 le4 = *(const bf16x4*)(LEp + ((size_t)(cu * 16 + cg) * 64 + lane) * 4);
            float s = acc[rt][ct][0] * (float)le4[0] + acc[rt][ct][1] * (float)le4[1]
                    + acc[rt][ct][2] * (float)le4[2] + acc[rt][ct][3] * (float)le4[3];
            s += __shfl_xor(s, 16, 64);   // reduce over lane-group bit 0 (basis)
            s += __shfl_xor(s, 32, 64);   // reduce over lane-group bit 1 (basis)
            if (lane < 16)
                equ[(size_t)n * 256 + c0 + ct * 16 + lane] = s * 0.0625f;
        }
    }
}

// ---------------------------------------------------------------------------
// Output: out = LIW[up] + [cur_inv | equ] @ W_mlp[256:768,:]
// K=512 handled as two K-ranges with different A sources.
// ---------------------------------------------------------------------------
__global__ __launch_bounds__(256) void k_out(
    const float* __restrict__ cur_inv, const float* __restrict__ equ,
    const bf16x8* __restrict__ packW, const float* __restrict__ LIW,
    const int* __restrict__ up, float* __restrict__ out)
{
    const int lane = threadIdx.x & 63, wid = threadIdx.x >> 6;
    const int row0 = blockIdx.x * 64;
    const int c0 = blockIdx.y * 256 + wid * 64;
    const int g = lane >> 4, r15 = lane & 15;
    f32x4 acc[4][4] = {};
    gemm_range(cur_inv, 256, N_FINE, row0, packW, 512, c0, 0, 8, acc, lane);
    gemm_range(equ,     256, N_FINE, row0, packW, 512, c0, 8, 16, acc, lane);
    #pragma unroll
    for (int rt = 0; rt < 4; ++rt)
        #pragma unroll
        for (int j = 0; j < 4; ++j) {
            int r = row0 + rt * 16 + g * 4 + j;
            if (r < N_FINE) {
                int cu = up[r];
                #pragma unroll
                for (int ct = 0; ct < 4; ++ct) {
                    int col = c0 + ct * 16 + r15;
                    out[(size_t)r * 512 + col] = acc[rt][ct][j] + LIW[(size_t)cu * 512 + col];
                }
            }
        }
}

extern "C" void kernel_launch(void* const* d_in, const int* in_sizes, int n_in,
                              void* d_out, int out_size, void* d_ws, size_t ws_size,
                              hipStream_t stream) {
    const float* last_inv = (const float*)d_in[0];
    const float* cur_inv  = (const float*)d_in[1];
    const float* last_equ = (const float*)d_in[2];
    const float* cur_equ  = (const float*)d_in[3];
    const int*   up       = (const int*)d_in[4];
    const float* W_le     = (const float*)d_in[5];
    const float* W_ce     = (const float*)d_in[6];
    const float* W_mlp    = (const float*)d_in[7];
    float* out = (float*)d_out;

    // workspace carve-up (all 256B-aligned by construction; total ~180.3 MB)
    char* w = (char*)d_ws;
    __bf16* LEp    = (__bf16*)w;  w += (size_t)N_COARSE * 16 * 64 * 4 * 2; // 102.4 MB
    float*  LIW    = (float*)w;   w += (size_t)N_COARSE * 512 * 4;        //  25.6 MB
    float*  equ    = (float*)w;   w += (size_t)N_FINE * 256 * 4;          //  51.2 MB
    __bf16* packLE = (__bf16*)w;  w += (size_t)32 * 256 * 8 * 2;
    __bf16* packCE = (__bf16*)w;  w += (size_t)32 * 256 * 8 * 2;
    __bf16* packM1 = (__bf16*)w;  w += (size_t)32 * 512 * 8 * 2;
    __bf16* packM2 = (__bf16*)w;  w += (size_t)64 * 512 * 8 * 2;

    // weight pre-pack (tiny, L2-resident afterwards)
    k_pack<<<(256 * 256 + 255) / 256, 256, 0, stream>>>(W_le,  packLE, 256, 256, 0);
    k_pack<<<(256 * 256 + 255) / 256, 256, 0, stream>>>(W_ce,  packCE, 256, 256, 0);
    k_pack<<<(256 * 512 + 255) / 256, 256, 0, stream>>>(W_mlp, packM1, 256, 512, 0);
    k_pack<<<(512 * 512 + 255) / 256, 256, 0, stream>>>(W_mlp, packM2, 512, 512, 256);

    // coarse-resolution transforms (linear commutes with gather)
    k_coarse_equ<<<N_COARSE * 16 / 64, 256, 0, stream>>>(
        last_equ, (const bf16x8*)packLE, LEp);
    k_coarse_inv<<<dim3((N_COARSE + 63) / 64, 2), 256, 0, stream>>>(
        last_inv, (const bf16x8*)packM1, LIW);

    // fine: fused CE GEMM + gathered-LE product + basis mean
    k_fine_equ<<<N_FINE * 16 / 64, 256, 0, stream>>>(
        cur_equ, (const bf16x8*)packCE, LEp, up, equ);

    // output MLP + gathered coarse contribution
    k_out<<<dim3((N_FINE + 63) / 64, 2), 256, 0, stream>>>(
        cur_inv, equ, (const bf16x8*)packM2, LIW, up, out);
}

// Round 2
// 613.855 us; speedup vs baseline: 1.2746x; 1.2746x over previous
//
#include <hip/hip_runtime.h>
#include <hip/hip_bf16.h>

#define N_COARSE 12500
#define N_FINE   50000

typedef __bf16 bf16x8 __attribute__((ext_vector_type(8)));
typedef __bf16 bf16x4 __attribute__((ext_vector_type(4)));
typedef float  f32x4  __attribute__((ext_vector_type(4)));

// ---------------------------------------------------------------------------
// Fragment conventions (v_mfma_f32_16x16x32_bf16), same as round 1 (verified):
//   a-frag: lane holds A[row = lane&15][k = (lane>>4)*8 + j]
//   b-frag: lane holds B[k = (lane>>4)*8 + j][col = lane&15]
//   d     : lane holds D[row = (lane>>4)*4 + j][col = lane&15]
// ---------------------------------------------------------------------------

__device__ __forceinline__ bf16x8 cvt8(f32x4 x, f32x4 y) {
    bf16x8 r;
    r[0] = (__bf16)x[0]; r[1] = (__bf16)x[1]; r[2] = (__bf16)x[2]; r[3] = (__bf16)x[3];
    r[4] = (__bf16)y[0]; r[5] = (__bf16)y[1]; r[6] = (__bf16)y[2]; r[7] = (__bf16)y[3];
    return r;
}

// ---- LDS A-tile: [64 rows][256 bf16] = 32 KB, XOR-swizzled ----------------
// Row stride 512 B would put lanes 0-15 (rows) all in bank 0 on ds_read_b128;
// byte ^= (row&7)<<4 spreads 8 rows across 8 distinct 16B slots (G4 recipe).
__device__ __forceinline__ int swz(int row, int byte) { return byte ^ ((row & 7) << 4); }

__device__ __forceinline__ void st_a(__bf16* lds, int row, int cs, bf16x8 v) {
    *(bf16x8*)((char*)lds + swz(row, row * 512 + cs * 16)) = v;
}
__device__ __forceinline__ bf16x8 ld_a(const __bf16* lds, int row, int ka) {
    return *(const bf16x8*)((const char*)lds + swz(row, row * 512 + ka * 2));
}

// stage 64 consecutive f32 rows (256 cols) -> bf16 LDS tile; coalesced loads
__device__ __forceinline__ void stage_f32(const float* __restrict__ A, long row0,
                                          __bf16* lds, int tid, long maxrow) {
    const int r0 = tid >> 5, cs = tid & 31;
    #pragma unroll
    for (int i = 0; i < 8; ++i) {
        int row = r0 + i * 8;
        long gr = row0 + row; if (gr > maxrow) gr = maxrow;
        const float* p = A + gr * 256 + cs * 8;
        f32x4 x = *(const f32x4*)p, y = *(const f32x4*)(p + 4);
        st_a(lds, row, cs, cvt8(x, y));
    }
}

// 64x64-per-wave MFMA over one 256-wide K segment, A from LDS, B from packed
// global (L2-resident). ksb = segment base in 32-wide K fragments.
__device__ __forceinline__ void mfma_tile(const __bf16* lds, const bf16x8* __restrict__ packB,
                                          int N, int c0, int ksb,
                                          f32x4 (&acc)[4][4], int lane) {
    const int g = lane >> 4, r15 = lane & 15;
    #pragma unroll
    for (int ks = 0; ks < 8; ++ks) {
        bf16x8 a[4];
        #pragma unroll
        for (int rt = 0; rt < 4; ++rt)
            a[rt] = ld_a(lds, rt * 16 + r15, ks * 32 + g * 8);
        const size_t kb = (size_t)((ksb + ks) * 4 + g) * N;
        #pragma unroll
        for (int ct = 0; ct < 4; ++ct) {
            bf16x8 b = packB[kb + c0 + ct * 16 + r15];
            #pragma unroll
            for (int rt = 0; rt < 4; ++rt)
                acc[rt][ct] = __builtin_amdgcn_mfma_f32_16x16x32_bf16(a[rt], b, acc[rt][ct], 0, 0, 0);
        }
    }
}

// ---------------------------------------------------------------------------
// Weight pre-pack: W(f32 [K x N]) -> bf16 frag layout [(k>>3)*N + n]*8 + (k&7)
// ---------------------------------------------------------------------------
__global__ __launch_bounds__(256) void k_pack(const float* __restrict__ W,
                                              __bf16* __restrict__ dst, int K, int N) {
    int idx = blockIdx.x * 256 + threadIdx.x;
    if (idx >= K * N) return;
    int k = idx / N, n = idx % N;
    dst[((size_t)(k >> 3) * N + n) * 8 + (k & 7)] = (__bf16)W[(size_t)k * N + n];
}

// f32 -> bf16 bulk convert (for last_inv)
__global__ __launch_bounds__(256) void k_cvt(const float* __restrict__ src,
                                             __bf16* __restrict__ dst, int n4) {
    int i = blockIdx.x * 256 + threadIdx.x;
    if (i >= n4) return;
    f32x4 v = ((const f32x4*)src)[i];
    bf16x4 o;
    o[0] = (__bf16)v[0]; o[1] = (__bf16)v[1]; o[2] = (__bf16)v[2]; o[3] = (__bf16)v[3];
    ((bf16x4*)dst)[i] = o;
}

// ---------------------------------------------------------------------------
// Coarse: LE = last_equ @ W_last_equ, stored bf16 in MFMA D-layout:
// LEp[((coarse*16 + cg)*64 + lane)*4 + j]  (8 KB contiguous per coarse point)
// ---------------------------------------------------------------------------
__global__ __launch_bounds__(256) void k_coarse_equ(
    const float* __restrict__ last_equ, const bf16x8* __restrict__ packW,
    __bf16* __restrict__ LEp)
{
    __shared__ __attribute__((aligned(16))) __bf16 As[64 * 256];
    const int tid = threadIdx.x, lane = tid & 63, wid = tid >> 6;
    const long row0 = (long)blockIdx.x * 64;
    stage_f32(last_equ, row0, As, tid, (long)N_COARSE * 16 - 1);
    __syncthreads();
    f32x4 acc[4][4] = {};
    mfma_tile(As, packW, 256, wid * 64, 0, acc, lane);
    #pragma unroll
    for (int rt = 0; rt < 4; ++rt) {
        int coarse = (int)(row0 >> 4) + rt;
        #pragma unroll
        for (int ct = 0; ct < 4; ++ct) {
            int cg = wid * 4 + ct;
            bf16x4 v;
            v[0] = (__bf16)acc[rt][ct][0]; v[1] = (__bf16)acc[rt][ct][1];
            v[2] = (__bf16)acc[rt][ct][2]; v[3] = (__bf16)acc[rt][ct][3];
            *(bf16x4*)(LEp + ((size_t)(coarse * 16 + cg) * 64 + lane) * 4) = v;
        }
    }
}

// ---------------------------------------------------------------------------
// Fine fused: CE = cur_equ @ W_cur_equ (LDS-staged MFMA), x gathered LE frag,
// mean over 16 basis rows -> equ (bf16). LE gathers issued at t=0 so their
// latency drains under the A-staging phase, not as an epilogue tail.
// ---------------------------------------------------------------------------
__global__ __launch_bounds__(256) void k_fine_equ(
    const float* __restrict__ cur_equ, const bf16x8* __restrict__ packW,
    const __bf16* __restrict__ LEp, const int* __restrict__ up,
    __bf16* __restrict__ equ)
{
    __shared__ __attribute__((aligned(16))) __bf16 As[64 * 256];
    const int tid = threadIdx.x, lane = tid & 63, wid = tid >> 6;
    const int n0 = blockIdx.x * 4;
    const long row0 = (long)blockIdx.x * 64;

    // prefetch LE fragments for this wave's 16 (point, colgrp) pairs
    int cu[4];
    #pragma unroll
    for (int rt = 0; rt < 4; ++rt) cu[rt] = up[n0 + rt];   // uniform -> s_load
    bf16x4 le[4][4];
    #pragma unroll
    for (int rt = 0; rt < 4; ++rt)
        #pragma unroll
        for (int ct = 0; ct < 4; ++ct)
            le[rt][ct] = *(const bf16x4*)(LEp +
                ((size_t)(cu[rt] * 16 + wid * 4 + ct) * 64 + lane) * 4);

    stage_f32(cur_equ, row0, As, tid, (long)N_FINE * 16 - 1);
    __syncthreads();
    f32x4 acc[4][4] = {};
    mfma_tile(As, packW, 256, wid * 64, 0, acc, lane);

    #pragma unroll
    for (int rt = 0; rt < 4; ++rt) {
        int n = n0 + rt;
        #pragma unroll
        for (int ct = 0; ct < 4; ++ct) {
            float s = acc[rt][ct][0] * (float)le[rt][ct][0]
                    + acc[rt][ct][1] * (float)le[rt][ct][1]
                    + acc[rt][ct][2] * (float)le[rt][ct][2]
                    + acc[rt][ct][3] * (float)le[rt][ct][3];
            s += __shfl_xor(s, 16, 64);   // basis reduce over lane-group bit 0
            s += __shfl_xor(s, 32, 64);   // basis reduce over lane-group bit 1
            if (lane < 16)
                equ[(size_t)n * 256 + wid * 64 + ct * 16 + lane] = (__bf16)(s * 0.0625f);
        }
    }
}

// ---------------------------------------------------------------------------
// Output: out = [ last_inv[up] | cur_inv | equ ] @ W_mlp   (K = 768)
// The coarse gather is K-rows 0-255 of the GEMM A -> latency hidden inside
// the pipelined K loop; no epilogue gather, no LIW precompute.
// ---------------------------------------------------------------------------
__global__ __launch_bounds__(256) void k_out(
    const __bf16* __restrict__ li_bf, const float* __restrict__ cur_inv,
    const __bf16* __restrict__ equ, const bf16x8* __restrict__ packW,
    const int* __restrict__ up, float* __restrict__ out)
{
    __shared__ __attribute__((aligned(16))) __bf16 As[64 * 256];
    const int tid = threadIdx.x, lane = tid & 63, wid = tid >> 6;
    const int row0 = blockIdx.x * 64;
    const int c0 = blockIdx.y * 256 + wid * 64;
    const int r0 = tid >> 5, cs = tid & 31;
    f32x4 acc[4][4] = {};

    // ---- segment 0: gathered last_inv rows (bf16) ----
    #pragma unroll
    for (int i = 0; i < 8; ++i) {
        int row = r0 + i * 8;
        int gr = row0 + row; if (gr > N_FINE - 1) gr = N_FINE - 1;
        st_a(As, row, cs, *(const bf16x8*)(li_bf + (size_t)up[gr] * 256 + cs * 8));
    }
    __syncthreads();
    mfma_tile(As, packW, 512, c0, 0, acc, lane);
    __syncthreads();

    // ---- segment 1: cur_inv (f32) ----
    stage_f32(cur_inv, row0, As, tid, N_FINE - 1);
    __syncthreads();
    mfma_tile(As, packW, 512, c0, 8, acc, lane);
    __syncthreads();

    // ---- segment 2: equ (bf16) ----
    #pragma unroll
    for (int i = 0; i < 8; ++i) {
        int row = r0 + i * 8;
        int gr = row0 + row; if (gr > N_FINE - 1) gr = N_FINE - 1;
        st_a(As, row, cs, *(const bf16x8*)(equ + (size_t)gr * 256 + cs * 8));
    }
    __syncthreads();
    mfma_tile(As, packW, 512, c0, 16, acc, lane);

    const int g = lane >> 4, r15 = lane & 15;
    #pragma unroll
    for (int rt = 0; rt < 4; ++rt)
        #pragma unroll
        for (int j = 0; j < 4; ++j) {
            int r = row0 + rt * 16 + g * 4 + j;
            if (r < N_FINE)
                #pragma unroll
                for (int ct = 0; ct < 4; ++ct)
                    out[(size_t)r * 512 + c0 + ct * 16 + r15] = acc[rt][ct][j];
        }
}

extern "C" void kernel_launch(void* const* d_in, const int* in_sizes, int n_in,
                              void* d_out, int out_size, void* d_ws, size_t ws_size,
                              hipStream_t stream) {
    const float* last_inv = (const float*)d_in[0];
    const float* cur_inv  = (const float*)d_in[1];
    const float* last_equ = (const float*)d_in[2];
    const float* cur_equ  = (const float*)d_in[3];
    const int*   up       = (const int*)d_in[4];
    const float* W_le     = (const float*)d_in[5];
    const float* W_ce     = (const float*)d_in[6];
    const float* W_mlp    = (const float*)d_in[7];
    float* out = (float*)d_out;

    // workspace carve-up (~135 MB)
    char* w = (char*)d_ws;
    __bf16* LEp    = (__bf16*)w;  w += (size_t)N_COARSE * 16 * 256 * 2;  // 102.4 MB
    __bf16* equ    = (__bf16*)w;  w += (size_t)N_FINE * 256 * 2;        //  25.6 MB
    __bf16* li_bf  = (__bf16*)w;  w += (size_t)N_COARSE * 256 * 2;      //   6.4 MB
    __bf16* packLE = (__bf16*)w;  w += (size_t)256 * 256 * 2;
    __bf16* packCE = (__bf16*)w;  w += (size_t)256 * 256 * 2;
    __bf16* packM  = (__bf16*)w;  w += (size_t)768 * 512 * 2;

    k_pack<<<256, 256, 0, stream>>>(W_le, packLE, 256, 256);
    k_pack<<<256, 256, 0, stream>>>(W_ce, packCE, 256, 256);
    k_pack<<<1536, 256, 0, stream>>>(W_mlp, packM, 768, 512);
    k_cvt<<<3125, 256, 0, stream>>>(last_inv, li_bf, N_COARSE * 256 / 4);

    k_coarse_equ<<<N_COARSE * 16 / 64, 256, 0, stream>>>(
        last_equ, (const bf16x8*)packLE, LEp);

    k_fine_equ<<<N_FINE / 4, 256, 0, stream>>>(
        cur_equ, (const bf16x8*)packCE, LEp, up, equ);

    k_out<<<dim3((N_FINE + 63) / 64, 2), 256, 0, stream>>>(
        li_bf, cur_inv, equ, (const bf16x8*)packM, up, out);
}

// Round 3
// 581.120 us; speedup vs baseline: 1.3464x; 1.0563x over previous
//
#include <hip/hip_runtime.h>
#include <hip/hip_bf16.h>

#define N_COARSE 12500
#define N_FINE   50000

typedef __bf16 bf16x8 __attribute__((ext_vector_type(8)));
typedef __bf16 bf16x4 __attribute__((ext_vector_type(4)));
typedef float  f32x4  __attribute__((ext_vector_type(4)));

// ---------------------------------------------------------------------------
// Fragment conventions (v_mfma_f32_16x16x32_bf16), HW-verified:
//   a-frag: lane holds A[row = lane&15][k = (lane>>4)*8 + j]
//   b-frag: lane holds B[k = (lane>>4)*8 + j][col = lane&15]
//   d     : lane holds D[row = (lane>>4)*4 + j][col = lane&15]
// ---------------------------------------------------------------------------

__device__ __forceinline__ bf16x8 cvt8(f32x4 x, f32x4 y) {
    bf16x8 r;
    r[0] = (__bf16)x[0]; r[1] = (__bf16)x[1]; r[2] = (__bf16)x[2]; r[3] = (__bf16)x[3];
    r[4] = (__bf16)y[0]; r[5] = (__bf16)y[1]; r[6] = (__bf16)y[2]; r[7] = (__bf16)y[3];
    return r;
}

// ---- LDS A-tile: [64 rows][256 bf16] = 32 KB, XOR-swizzled ----------------
// byte ^= (row&7)<<4 spreads the 16 row-lanes of a ds_read_b128 across 8
// distinct 16B slots (G4 recipe) instead of one bank.
__device__ __forceinline__ int swz(int row, int byte) { return byte ^ ((row & 7) << 4); }

__device__ __forceinline__ void st_a(__bf16* lds, int row, int cs, bf16x8 v) {
    *(bf16x8*)((char*)lds + swz(row, row * 512 + cs * 16)) = v;
}
__device__ __forceinline__ bf16x8 ld_a(const __bf16* lds, int row, int ka) {
    return *(const bf16x8*)((const char*)lds + swz(row, row * 512 + ka * 2));
}

// stage 64 consecutive f32 rows (256 cols) -> bf16 LDS tile; coalesced loads
template<int NT>
__device__ __forceinline__ void stage_f32(const float* __restrict__ A, long row0,
                                          __bf16* lds, int tid, long maxrow) {
    const int r0 = tid >> 5, cs = tid & 31;
    constexpr int RPI = NT / 32;
    #pragma unroll
    for (int i = 0; i < 64 / RPI; ++i) {
        int row = r0 + i * RPI;
        long gr = row0 + row; if (gr > maxrow) gr = maxrow;
        const float* p = A + gr * 256 + cs * 8;
        f32x4 x = *(const f32x4*)p, y = *(const f32x4*)(p + 4);
        st_a(lds, row, cs, cvt8(x, y));
    }
}

// 64x64-per-wave MFMA over one 256-wide K segment, A from LDS, B from packed
// global (L2-resident). ksb = segment base in 32-wide K fragments.
__device__ __forceinline__ void mfma_tile(const __bf16* lds, const bf16x8* __restrict__ packB,
                                          int N, int c0, int ksb,
                                          f32x4 (&acc)[4][4], int lane) {
    const int g = lane >> 4, r15 = lane & 15;
    #pragma unroll
    for (int ks = 0; ks < 8; ++ks) {
        bf16x8 a[4];
        #pragma unroll
        for (int rt = 0; rt < 4; ++rt)
            a[rt] = ld_a(lds, rt * 16 + r15, ks * 32 + g * 8);
        const size_t kb = (size_t)((ksb + ks) * 4 + g) * N;
        #pragma unroll
        for (int ct = 0; ct < 4; ++ct) {
            bf16x8 b = packB[kb + c0 + ct * 16 + r15];
            #pragma unroll
            for (int rt = 0; rt < 4; ++rt)
                acc[rt][ct] = __builtin_amdgcn_mfma_f32_16x16x32_bf16(a[rt], b, acc[rt][ct], 0, 0, 0);
        }
    }
}

// ---------------------------------------------------------------------------
// Weight pre-pack: W(f32 [K x N]) -> bf16 frag layout [(k>>3)*N + n]*8 + (k&7)
// ---------------------------------------------------------------------------
__global__ __launch_bounds__(256) void k_pack(const float* __restrict__ W,
                                              __bf16* __restrict__ dst, int K, int N) {
    int idx = blockIdx.x * 256 + threadIdx.x;
    if (idx >= K * N) return;
    int k = idx / N, n = idx % N;
    dst[((size_t)(k >> 3) * N + n) * 8 + (k & 7)] = (__bf16)W[(size_t)k * N + n];
}

// f32 -> bf16 bulk convert (for last_inv)
__global__ __launch_bounds__(256) void k_cvt(const float* __restrict__ src,
                                             __bf16* __restrict__ dst, int n4) {
    int i = blockIdx.x * 256 + threadIdx.x;
    if (i >= n4) return;
    f32x4 v = ((const f32x4*)src)[i];
    bf16x4 o;
    o[0] = (__bf16)v[0]; o[1] = (__bf16)v[1]; o[2] = (__bf16)v[2]; o[3] = (__bf16)v[3];
    ((bf16x4*)dst)[i] = o;
}

// ---------------------------------------------------------------------------
// Coarse: LE = last_equ @ W_last_equ, stored bf16 in MFMA D-layout:
// LEp[((coarse*16 + cg)*64 + lane)*4 + j]  (8 KB contiguous per coarse point)
// ---------------------------------------------------------------------------
__global__ __launch_bounds__(256) void k_coarse_equ(
    const float* __restrict__ last_equ, const bf16x8* __restrict__ packW,
    __bf16* __restrict__ LEp)
{
    __shared__ __attribute__((aligned(16))) __bf16 As[64 * 256];
    const int tid = threadIdx.x, lane = tid & 63, wid = tid >> 6;
    const long row0 = (long)blockIdx.x * 64;
    stage_f32<256>(last_equ, row0, As, tid, (long)N_COARSE * 16 - 1);
    __syncthreads();
    f32x4 acc[4][4] = {};
    mfma_tile(As, packW, 256, wid * 64, 0, acc, lane);
    #pragma unroll
    for (int rt = 0; rt < 4; ++rt) {
        int coarse = (int)(row0 >> 4) + rt;
        #pragma unroll
        for (int ct = 0; ct < 4; ++ct) {
            int cg = wid * 4 + ct;
            bf16x4 v;
            v[0] = (__bf16)acc[rt][ct][0]; v[1] = (__bf16)acc[rt][ct][1];
            v[2] = (__bf16)acc[rt][ct][2]; v[3] = (__bf16)acc[rt][ct][3];
            *(bf16x4*)(LEp + ((size_t)(coarse * 16 + cg) * 64 + lane) * 4) = v;
        }
    }
}

// ---------------------------------------------------------------------------
// Fine fused: CE = cur_equ @ W_cur_equ (LDS-staged MFMA), x gathered LE frag,
// mean over 16 basis rows -> equ (bf16).
// Order matters: staging loads issued FIRST, LE gathers second -> the LDS
// writes' vmcnt wait doesn't drain the gathers (FIFO), so gathers stay in
// flight across the barrier and complete under the MFMA phase.
// ---------------------------------------------------------------------------
__global__ __launch_bounds__(256) void k_fine_equ(
    const float* __restrict__ cur_equ, const bf16x8* __restrict__ packW,
    const __bf16* __restrict__ LEp, const int* __restrict__ up,
    __bf16* __restrict__ equ)
{
    __shared__ __attribute__((aligned(16))) __bf16 As[64 * 256];
    const int tid = threadIdx.x, lane = tid & 63, wid = tid >> 6;
    const int n0 = blockIdx.x * 4;
    const long row0 = (long)blockIdx.x * 64;

    int cu[4];
    #pragma unroll
    for (int rt = 0; rt < 4; ++rt) cu[rt] = up[n0 + rt];   // uniform -> s_load

    stage_f32<256>(cur_equ, row0, As, tid, (long)N_FINE * 16 - 1);

    // LE fragment gathers (issued after staging loads; consumed post-MFMA)
    bf16x4 le[4][4];
    #pragma unroll
    for (int rt = 0; rt < 4; ++rt)
        #pragma unroll
        for (int ct = 0; ct < 4; ++ct)
            le[rt][ct] = *(const bf16x4*)(LEp +
                ((size_t)(cu[rt] * 16 + wid * 4 + ct) * 64 + lane) * 4);

    __syncthreads();
    f32x4 acc[4][4] = {};
    mfma_tile(As, packW, 256, wid * 64, 0, acc, lane);

    #pragma unroll
    for (int rt = 0; rt < 4; ++rt) {
        int n = n0 + rt;
        #pragma unroll
        for (int ct = 0; ct < 4; ++ct) {
            float s = acc[rt][ct][0] * (float)le[rt][ct][0]
                    + acc[rt][ct][1] * (float)le[rt][ct][1]
                    + acc[rt][ct][2] * (float)le[rt][ct][2]
                    + acc[rt][ct][3] * (float)le[rt][ct][3];
            s += __shfl_xor(s, 16, 64);   // basis reduce over lane-group bit 0
            s += __shfl_xor(s, 32, 64);   // basis reduce over lane-group bit 1
            if (lane < 16)
                equ[(size_t)n * 256 + wid * 64 + ct * 16 + lane] = (__bf16)(s * 0.0625f);
        }
    }
}

// ---------------------------------------------------------------------------
// Output: out = [ last_inv[up] | cur_inv | equ ] @ W_mlp   (K = 768)
// 512 threads / 8 waves: all 512 output columns from ONE staging pass
// (halves A traffic vs the previous blockIdx.y=2 version).
// ---------------------------------------------------------------------------
__global__ __launch_bounds__(512) void k_out(
    const __bf16* __restrict__ li_bf, const float* __restrict__ cur_inv,
    const __bf16* __restrict__ equ, const bf16x8* __restrict__ packW,
    const int* __restrict__ up, float* __restrict__ out)
{
    __shared__ __attribute__((aligned(16))) __bf16 As[64 * 256];
    const int tid = threadIdx.x, lane = tid & 63, wid = tid >> 6;
    const int row0 = blockIdx.x * 64;
    const int c0 = wid * 64;
    const int r0 = tid >> 5, cs = tid & 31;
    f32x4 acc[4][4] = {};

    // ---- segment 0: gathered last_inv rows (bf16) ----
    #pragma unroll
    for (int i = 0; i < 4; ++i) {
        int row = r0 + i * 16;
        int gr = row0 + row; if (gr > N_FINE - 1) gr = N_FINE - 1;
        st_a(As, row, cs, *(const bf16x8*)(li_bf + (size_t)up[gr] * 256 + cs * 8));
    }
    __syncthreads();
    mfma_tile(As, packW, 512, c0, 0, acc, lane);
    __syncthreads();

    // ---- segment 1: cur_inv (f32) ----
    stage_f32<512>(cur_inv, row0, As, tid, N_FINE - 1);
    __syncthreads();
    mfma_tile(As, packW, 512, c0, 8, acc, lane);
    __syncthreads();

    // ---- segment 2: equ (bf16) ----
    #pragma unroll
    for (int i = 0; i < 4; ++i) {
        int row = r0 + i * 16;
        int gr = row0 + row; if (gr > N_FINE - 1) gr = N_FINE - 1;
        st_a(As, row, cs, *(const bf16x8*)(equ + (size_t)gr * 256 + cs * 8));
    }
    __syncthreads();
    mfma_tile(As, packW, 512, c0, 16, acc, lane);

    const int g = lane >> 4, r15 = lane & 15;
    #pragma unroll
    for (int rt = 0; rt < 4; ++rt)
        #pragma unroll
        for (int j = 0; j < 4; ++j) {
            int r = row0 + rt * 16 + g * 4 + j;
            if (r < N_FINE)
                #pragma unroll
                for (int ct = 0; ct < 4; ++ct)
                    out[(size_t)r * 512 + c0 + ct * 16 + r15] = acc[rt][ct][j];
        }
}

extern "C" void kernel_launch(void* const* d_in, const int* in_sizes, int n_in,
                              void* d_out, int out_size, void* d_ws, size_t ws_size,
                              hipStream_t stream) {
    const float* last_inv = (const float*)d_in[0];
    const float* cur_inv  = (const float*)d_in[1];
    const float* last_equ = (const float*)d_in[2];
    const float* cur_equ  = (const float*)d_in[3];
    const int*   up       = (const int*)d_in[4];
    const float* W_le     = (const float*)d_in[5];
    const float* W_ce     = (const float*)d_in[6];
    const float* W_mlp    = (const float*)d_in[7];
    float* out = (float*)d_out;

    // workspace carve-up (~135 MB)
    char* w = (char*)d_ws;
    __bf16* LEp    = (__bf16*)w;  w += (size_t)N_COARSE * 16 * 256 * 2;  // 102.4 MB
    __bf16* equ    = (__bf16*)w;  w += (size_t)N_FINE * 256 * 2;        //  25.6 MB
    __bf16* li_bf  = (__bf16*)w;  w += (size_t)N_COARSE * 256 * 2;      //   6.4 MB
    __bf16* packLE = (__bf16*)w;  w += (size_t)256 * 256 * 2;
    __bf16* packCE = (__bf16*)w;  w += (size_t)256 * 256 * 2;
    __bf16* packM  = (__bf16*)w;  w += (size_t)768 * 512 * 2;

    k_pack<<<256, 256, 0, stream>>>(W_le, packLE, 256, 256);
    k_pack<<<256, 256, 0, stream>>>(W_ce, packCE, 256, 256);
    k_pack<<<1536, 256, 0, stream>>>(W_mlp, packM, 768, 512);
    k_cvt<<<3125, 256, 0, stream>>>(last_inv, li_bf, N_COARSE * 256 / 4);

    k_coarse_equ<<<N_COARSE * 16 / 64, 256, 0, stream>>>(
        last_equ, (const bf16x8*)packLE, LEp);

    k_fine_equ<<<N_FINE / 4, 256, 0, stream>>>(
        cur_equ, (const bf16x8*)packCE, LEp, up, equ);

    k_out<<<(N_FINE + 63) / 64, 512, 0, stream>>>(
        li_bf, cur_inv, equ, (const bf16x8*)packM, up, out);
}